// Round 1
// baseline (137.708 us; speedup 1.0000x reference)
//
#include <hip/hip_runtime.h>
#include <math.h>

// Biquad highpass IIR over [B=128, C=2, T=65536] f32.
// R5: chunk length 64 -> 256 (warm-up ratio 2.0x -> 1.25x of reads, compute
// -37%), 1024 single-wave blocks = exactly 4/CU = one dispatch generation.
// 10 tiles/wave through the same 2x8KiB double-buffer with the proven
// conflict-free DMA lane permutation. Live tiles processed as 4 pairs; each
// pair's output staged LDS->VGPR, then next pair's DMA issued BEFORE the
// 16 global stores (vmcnt order: loads first), so steady-state waits are
// counted vmcnt(24)/vmcnt(16) and the read pipe never drains. Each store
// phase writes full 256B sectors (16 lanes cover one chunk's 64-sample pair
// region contiguously) -- keeps R4's write-amplification fix while spreading
// writes across the whole wave lifetime (R/W mixed stream instead of one
// terminal 16KiB burst).
// Numerics: W=64 zero-state warm-up (pole radius 0.8234 => boundary error
// ~4e-6, now at 4x fewer boundaries); absmax floor 0.0156 = f32 contraction
// noise, proven R1-R4.

#define T_LEN    65536
#define L_CHUNK  256
#define W_WARM   64
#define TS       32
#define BLK      64                  // one wave per block
#define ROWS     64                  // chunks per wave
#define BUF_F    (ROWS * TS)         // 2048 floats = 8 KiB per buffer
#define BLOCKS_PER_CH ((T_LEN / L_CHUNK) / ROWS)   // 4
#define N_TILES  ((L_CHUNK + W_WARM) / TS)         // 10
#define N_PAIRS  ((N_TILES - 2) / 2)               // 4 live pairs

#define WAITVM(n) asm volatile("s_waitcnt vmcnt(" #n ")" ::: "memory")

__device__ __forceinline__ void lds_fence() {
    // orders DS ops (in-order per wave; block = one wave) without draining vmcnt
    asm volatile("s_waitcnt lgkmcnt(0)" ::: "memory");
}

// DMA one 8 KiB tile into LDS. Instr i writes lane k's 16B to buf+i*1024+k*16.
// Global source permuted so LDS slot q=i*64+lane holds row l=q>>3's float4
// #j where j=((q&7)-l)&7  (=> compute reads at slot l*8+((g+l)&7) are
// bank-conflict-free). Row stride in global memory is L_CHUNK floats.
__device__ __forceinline__ void dma_tile(const float* __restrict__ x,
                                         int base_f, int tile, float* buf)
{
    #pragma unroll
    for (int i = 0; i < 8; ++i) {
        int pos = base_f + i * (8 * L_CHUNK) + tile * TS;
        pos = pos < 0 ? 0 : pos;     // global chunk 0 pre-signal clamp (zeroed later)
        __builtin_amdgcn_global_load_lds(
            (__attribute__((address_space(1))) void*)(void*)(x + pos),
            (__attribute__((address_space(3))) void*)(buf + i * 256),
            16, 0, 0);
    }
}

template <bool WARM>
__device__ __forceinline__ void tile_filter(float* buf, int lane, bool ch0,
    float c_b0, float c_b1, float c_b2, float c_a1, float c_a2,
    float& x1, float& x2, float& y1, float& y2)
{
    float4 r[8];
    #pragma unroll
    for (int g = 0; g < 8; ++g)
        r[g] = *(float4*)&buf[(lane * 8 + ((g + lane) & 7)) * 4];

    if (WARM && ch0) {   // channel-start row: pre-channel reads are garbage => state 0
        #pragma unroll
        for (int g = 0; g < 8; ++g) r[g] = make_float4(0.f, 0.f, 0.f, 0.f);
    }

    #pragma unroll
    for (int g = 0; g < 8; ++g) {
        float4 v = r[g];
        float yv;
        yv = c_b0*v.x + c_b1*x1 + c_b2*x2 - c_a1*y1 - c_a2*y2;
        x2 = x1; x1 = v.x; y2 = y1; y1 = yv; v.x = yv;
        yv = c_b0*v.y + c_b1*x1 + c_b2*x2 - c_a1*y1 - c_a2*y2;
        x2 = x1; x1 = v.y; y2 = y1; y1 = yv; v.y = yv;
        yv = c_b0*v.z + c_b1*x1 + c_b2*x2 - c_a1*y1 - c_a2*y2;
        x2 = x1; x1 = v.z; y2 = y1; y1 = yv; v.z = yv;
        yv = c_b0*v.w + c_b1*x1 + c_b2*x2 - c_a1*y1 - c_a2*y2;
        x2 = x1; x1 = v.w; y2 = y1; y1 = yv; v.w = yv;
        if (!WARM) r[g] = v;
    }

    if (!WARM) {         // in-place: staging buffer becomes output buffer
        #pragma unroll
        for (int g = 0; g < 8; ++g)
            *(float4*)&buf[(lane * 8 + ((g + lane) & 7)) * 4] = r[g];
    }
}

__global__ __launch_bounds__(BLK, 2)
void hp_biquad_kernel(const float* __restrict__ x, float* __restrict__ y,
                      float c_b0, float c_b1, float c_b2, float c_a1, float c_a2)
{
    __shared__ float bufA[BUF_F];
    __shared__ float bufB[BUF_F];
    const int lane = threadIdx.x;
    const int cg0  = blockIdx.x * ROWS;
    const bool ch0 = ((blockIdx.x & (BLOCKS_PER_CH - 1)) == 0) && (lane == 0);

    // per-lane DMA source base (floats): row l0 = lane>>3, permuted j0
    const int l0  = lane >> 3;
    const int j0  = ((lane & 7) - l0) & 7;
    const int bsf = (cg0 + l0) * L_CHUNK - W_WARM + j0 * 4;

    float x1 = 0.f, x2 = 0.f, y1 = 0.f, y2 = 0.f;

    // ---- prologue: warm tiles 0,1 (W=64), keep 2 tiles in flight ----
    dma_tile(x, bsf, 0, bufA);                 // out: 8
    dma_tile(x, bsf, 1, bufB);                 // out: 16

    WAITVM(8);                                  // t0 landed
    tile_filter<true>(bufA, lane, ch0, c_b0, c_b1, c_b2, c_a1, c_a2, x1, x2, y1, y2);
    lds_fence();                                // A's reads retired before refill
    dma_tile(x, bsf, 2, bufA);                 // out: <=8(t1) + 8

    WAITVM(8);                                  // t1 landed
    tile_filter<true>(bufB, lane, ch0, c_b0, c_b1, c_b2, c_a1, c_a2, x1, x2, y1, y2);
    lds_fence();
    dma_tile(x, bsf, 3, bufB);                 // out: <=8(t2) + 8

    // ---- 4 live pairs: tiles (2p+2, 2p+3). Steady-state vmcnt ordering
    // is [loads(16)][stores(16)], so vmcnt(24) <=> pair's A-tile landed,
    // vmcnt(16) <=> pair's B-tile landed; old stores proven retired by the
    // previous pair's vmcnt(16). Read pipe never drains after prologue. ----
    const int ybase = cg0 * L_CHUNK;
    #pragma unroll
    for (int p = 0; p < N_PAIRS; ++p) {
        if (p == 0) { WAITVM(8); } else { WAITVM(24); }   // A-tile landed
        tile_filter<false>(bufA, lane, ch0, c_b0, c_b1, c_b2, c_a1, c_a2, x1, x2, y1, y2);
        if (p == 0) { WAITVM(0); } else { WAITVM(16); }   // B-tile landed
        tile_filter<false>(bufB, lane, ch0, c_b0, c_b1, c_b2, c_a1, c_a2, x1, x2, y1, y2);
        lds_fence();                            // in-place writes before stage reads

        // stage pair output LDS -> regs (64 VGPR), freeing LDS for refill
        float4 v[16];
        #pragma unroll
        for (int k = 0; k < 16; ++k) {
            int q  = lane + k * 64;
            int sg = q >> 4;                    // chunk row 0..63
            int jj = q & 15;                    // float4 index within 64-sample pair
            float* b = (jj < 8) ? bufA : bufB;
            int g  = jj & 7;
            v[k] = *(float4*)&b[(sg * 8 + ((g + sg) & 7)) * 4];
        }
        lds_fence();                            // stage reads in regs; LDS reusable

        if (p < N_PAIRS - 1) {                  // issue next pair's loads FIRST
            dma_tile(x, bsf, 2 * p + 4, bufA);
            dma_tile(x, bsf, 2 * p + 5, bufB);
        }

        // full-256B-sector stores: instr k covers 4 chunks' complete
        // 64-sample pair regions (16 lanes contiguous per sector)
        #pragma unroll
        for (int k = 0; k < 16; ++k) {
            int q  = lane + k * 64;
            int sg = q >> 4;
            int jj = q & 15;
            *(float4*)(y + ybase + sg * L_CHUNK + p * 64 + jj * 4) = v[k];
        }
    }
}

extern "C" void kernel_launch(void* const* d_in, const int* in_sizes, int n_in,
                              void* d_out, int out_size, void* d_ws, size_t ws_size,
                              hipStream_t stream)
{
    const float* x = (const float*)d_in[0];
    float* y = (float*)d_out;

    // Same double-precision coefficient math as the reference, cast to f32.
    const double SR = 16000.0, FLO = 200.0, FHI = 1200.0;
    const double freq   = 0.5 * (FLO + FHI);      // 700 Hz
    const double cutoff = freq / SR;
    const double q      = 0.70710678;
    const double w0 = 2.0 * M_PI * cutoff;
    const double cw = cos(w0), sw = sin(w0);
    const double alpha = sw / (2.0 * q);
    const double b0 = (1.0 + cw) / 2.0;
    const double b1 = -(1.0 + cw);
    const double b2 = (1.0 + cw) / 2.0;
    const double a0 = 1.0 + alpha;
    const double a1 = -2.0 * cw;
    const double a2 = 1.0 - alpha;
    const float fb0 = (float)(b0 / a0), fb1 = (float)(b1 / a0), fb2 = (float)(b2 / a0);
    const float fa1 = (float)(a1 / a0), fa2 = (float)(a2 / a0);

    const int total  = 128 * 2 * T_LEN;            // 16,777,216 samples
    const int chunks = total / L_CHUNK;            // 65,536
    const int blocks = chunks / ROWS;              // 1024 single-wave blocks

    hp_biquad_kernel<<<blocks, BLK, 0, stream>>>(x, y, fb0, fb1, fb2, fa1, fa2);
    (void)in_sizes; (void)n_in; (void)out_size; (void)d_ws; (void)ws_size;
}